// Round 8
// baseline (125.710 us; speedup 1.0000x reference)
//
#include <hip/hip_runtime.h>

// vol [B=2, 192,192,192, C=1] fp32, affine [B,3,4] fp32,
// out [B,192,192,192,1] fp32.
#define DIM   192
#define PLANE (DIM * DIM)
#define NB    2
#define DPT   4   // d-voxels per thread (plane reuse + 16 loads in flight)
#define BH    4   // h rows per block (row reuse in L1 across waves)

typedef float f2 __attribute__((ext_vector_type(2), aligned(4)));

__global__ __launch_bounds__(256) void
SpatialTransformer_warp_kernel(const float* __restrict__ vol,
                               const float* __restrict__ affine,
                               float* __restrict__ out) {
    const int tid = threadIdx.x;
    const int w   = (blockIdx.x << 6) + (tid & 63);   // 64-lane wave along w
    const int h   = blockIdx.y * BH + (tid >> 6);     // 4 h rows per block
    const int z   = blockIdx.z;                       // (d-quad | b)
    const int b   = (z >= DIM / DPT) ? 1 : 0;
    const int d0  = (z - b * (DIM / DPT)) * DPT;

    const float* __restrict__ A = affine + b * 12;
    const float a00 = A[0], a01 = A[1], a02 = A[2],  a03 = A[3];
    const float a10 = A[4], a11 = A[5], a12 = A[6],  a13 = A[7];
    const float a20 = A[8], a21 = A[9], a22 = A[10], a23 = A[11];

    const float center = (DIM - 1) * 0.5f;   // 95.5
    const float maxl   = (float)(DIM - 1);   // 191.0
    const float maxi0  = (float)(DIM - 2);   // 190.0
    const float fplane = (float)PLANE;       // 36864.0
    const float fdim   = (float)DIM;         // 192.0

    const float ch = (float)h - center;
    const float cw = (float)w - center;

    // Partial sums independent of d
    const float pd = a01 * ch + a02 * cw + a03 + center;
    const float ph = a11 * ch + a12 * cw + a13 + center;
    const float pw = a21 * ch + a22 * cw + a23 + center;

    const float* __restrict__ vb = vol + (size_t)b * DIM * PLANE;
    float* __restrict__ ob = out + ((size_t)b * DIM + d0) * PLANE
                                 + (size_t)h * DIM + w;

    f2 r00[DPT], r01[DPT], r10[DPT], r11[DPT];
    float w0d_[DPT], w0h_[DPT], w0w_[DPT];

    // ---- batch: compute all addresses, issue all 16 loads ----
#pragma unroll
    for (int k = 0; k < DPT; ++k) {
        const float cd = (float)(d0 + k) - center;
        const float ld = a00 * cd + pd;
        const float lh = a10 * cd + ph;
        const float lw = a20 * cd + pw;

        // i0 = min(floor(clamp(l,0,191)),190); i1 = i0+1; w0 = i0+1 - clamp(l).
        // Identical to reference semantics (right-clamped corner has zero weight).
        const float td = __builtin_amdgcn_fmed3f(ld, 0.0f, maxl);
        const float th = __builtin_amdgcn_fmed3f(lh, 0.0f, maxl);
        const float tw = __builtin_amdgcn_fmed3f(lw, 0.0f, maxl);

        const float fd = fminf(floorf(td), maxi0);
        const float fh = fminf(floorf(th), maxi0);
        const float fw = fminf(floorf(tw), maxi0);

        w0d_[k] = fd + 1.0f - td;
        w0h_[k] = fh + 1.0f - th;
        w0w_[k] = fw + 1.0f - tw;

        // Flat index in float: all values integer-valued and < 2^24 -> exact.
        const int idx = (int)__builtin_fmaf(fd, fplane, __builtin_fmaf(fh, fdim, fw));
        const float* p = vb + idx;

        r00[k] = *(const f2*)(p);                   // (d0, h0, w0..w0+1)
        r01[k] = *(const f2*)(p + DIM);             // (d0, h0+1)
        r10[k] = *(const f2*)(p + PLANE);           // (d0+1, h0) — next k's (d0, h0)
        r11[k] = *(const f2*)(p + PLANE + DIM);     // (d0+1, h0+1)
    }

    // Hard scheduling fence: nothing crosses. Forces all 16 loads to be
    // issued (and their dest regs live) before any consume math — one
    // latency exposure for the whole batch instead of ~4 small drains.
    __builtin_amdgcn_sched_barrier(0);

    // ---- consume ----
#pragma unroll
    for (int k = 0; k < DPT; ++k) {
        const float w0w = w0w_[k], w1w = 1.0f - w0w;
        const float w0h = w0h_[k], w1h = 1.0f - w0h;
        const float w0d = w0d_[k], w1d = 1.0f - w0d;

        const float x00 = r00[k].x * w0w + r00[k].y * w1w;
        const float x01 = r01[k].x * w0w + r01[k].y * w1w;
        const float x10 = r10[k].x * w0w + r10[k].y * w1w;
        const float x11 = r11[k].x * w0w + r11[k].y * w1w;

        const float y0 = x00 * w0h + x01 * w1h;
        const float y1 = x10 * w0h + x11 * w1h;

        __builtin_nontemporal_store(y0 * w0d + y1 * w1d, ob + k * PLANE);
    }
}

extern "C" void kernel_launch(void* const* d_in, const int* in_sizes, int n_in,
                              void* d_out, int out_size, void* d_ws, size_t ws_size,
                              hipStream_t stream) {
    const float* vol    = (const float*)d_in[0];
    const float* affine = (const float*)d_in[1];
    float* out = (float*)d_out;

    dim3 grid(DIM / 64, DIM / BH, NB * (DIM / DPT));  // (w-tile, h-tile, d-quad|b)
    dim3 block(256);
    SpatialTransformer_warp_kernel<<<grid, block, 0, stream>>>(vol, affine, out);
}